// Round 4
// baseline (266.428 us; speedup 1.0000x reference)
//
#include <hip/hip_runtime.h>
#include <math.h>

// x [B=512, C=1024, H=8, W=8] f32. out same shape.
#define C_DIM 1024
#define HW 64
#define F4_PER_BATCH 16384  // C_DIM*HW/4
#define EPSV 1e-8f
#define TINYF 1.17549435e-38f

typedef float vfloat4 __attribute__((ext_vector_type(4)));

__device__ __forceinline__ void threefry2x32_01(unsigned x0, unsigned x1,
                                                unsigned& o0, unsigned& o1) {
    const unsigned ks0 = 0u, ks1 = 1u, ks2 = 0x1BD11BDBu; // 0x1BD11BDA ^ 0 ^ 1
    x0 += ks0; x1 += ks1;
#define TF_R(r) { x0 += x1; x1 = (x1 << (r)) | (x1 >> (32 - (r))); x1 ^= x0; }
    TF_R(13) TF_R(15) TF_R(26) TF_R(6)
    x0 += ks1; x1 += ks2 + 1u;
    TF_R(17) TF_R(29) TF_R(16) TF_R(24)
    x0 += ks2; x1 += ks0 + 2u;
    TF_R(13) TF_R(15) TF_R(26) TF_R(6)
    x0 += ks0; x1 += ks1 + 3u;
    TF_R(17) TF_R(29) TF_R(16) TF_R(24)
    x0 += ks1; x1 += ks2 + 4u;
    TF_R(13) TF_R(15) TF_R(26) TF_R(6)
    x0 += ks2; x1 += ks0 + 5u;
#undef TF_R
    o0 = x0; o1 = x1;
}

// jax_threefry_partitionable=True: counter (hi=0, lo=n), out = o0 ^ o1.
__device__ __forceinline__ unsigned jax_random_bits(unsigned n) {
    unsigned o0, o1;
    threefry2x32_01(0u, n, o0, o1);
    return o0 ^ o1;
}

__device__ __forceinline__ bool bad_val(float v) {
    return ((__float_as_uint(v) & 0x7F800000u) == 0x7F800000u) || (v < 0.0f);
}

// Order-preserving float<->uint encoding for unsigned atomicMax.
// encode(-inf)=0x007FFFFF > 0, so memset-0 acts as identity element.
__device__ __forceinline__ unsigned enc_f32(float f) {
    unsigned b = __float_as_uint(f);
    return (b & 0x80000000u) ? ~b : (b | 0x80000000u);
}
__device__ __forceinline__ float dec_f32(unsigned u) {
    unsigned b = (u & 0x80000000u) ? (u ^ 0x80000000u) : ~u;
    return __uint_as_float(b);
}

// ---- A1: channel-max partials. 4 blocks/batch, each streams 64 KB. --------
__global__ __launch_bounds__(256) void sa_max_kernel(
    const float* __restrict__ x, unsigned* __restrict__ maxenc)
{
    const int bid = blockIdx.x;       // 2048
    const int t = threadIdx.x;
    const int b = bid >> 2;
    const float4* __restrict__ xb = (const float4*)x + (size_t)bid * 4096;

    float4 pm = make_float4(-INFINITY, -INFINITY, -INFINITY, -INFINITY);
#pragma unroll 8
    for (int i = 0; i < 16; ++i) {
        float4 v = xb[t + 256 * i];
        pm.x = fmaxf(pm.x, v.x); pm.y = fmaxf(pm.y, v.y);
        pm.z = fmaxf(pm.z, v.z); pm.w = fmaxf(pm.w, v.w);
    }
    // reduce lanes with same (t&15) within the wave
#pragma unroll
    for (int off = 16; off <= 32; off <<= 1) {
        pm.x = fmaxf(pm.x, __shfl_xor(pm.x, off, 64));
        pm.y = fmaxf(pm.y, __shfl_xor(pm.y, off, 64));
        pm.z = fmaxf(pm.z, __shfl_xor(pm.z, off, 64));
        pm.w = fmaxf(pm.w, __shfl_xor(pm.w, off, 64));
    }
    __shared__ float4 red[4][16];
    const int wv = t >> 6, lane = t & 63;
    if (lane < 16) red[wv][lane] = pm;
    __syncthreads();
    if (t < 16) {
        float4 a = red[0][t];
#pragma unroll
        for (int w = 1; w < 4; ++w) {
            float4 o = red[w][t];
            a.x = fmaxf(a.x, o.x); a.y = fmaxf(a.y, o.y);
            a.z = fmaxf(a.z, o.z); a.w = fmaxf(a.w, o.w);
        }
        unsigned* dst = maxenc + b * 64 + t * 4;
        atomicMax(dst + 0, enc_f32(a.x));
        atomicMax(dst + 1, enc_f32(a.y));
        atomicMax(dst + 2, enc_f32(a.z));
        atomicMax(dst + 3, enc_f32(a.w));
    }
}

// ---- A2: tiny middle -> gate[B,64]. One wave per batch. -------------------
__global__ __launch_bounds__(64) void sa_middle_kernel(
    const unsigned* __restrict__ maxenc,
    const float* __restrict__ w11,
    const float* __restrict__ w5,
    const float* __restrict__ b5,
    const float* __restrict__ w6,
    const float* __restrict__ b6,
    float* __restrict__ gate_out)
{
    const int b = blockIdx.x;
    const int t = threadIdx.x;  // 0..63

    __shared__ float sm[64];
    __shared__ float sa16[16];
    __shared__ float sb16[16];
    __shared__ float so2[64];
    __shared__ float shid[4 * 64];

    sm[t] = dec_f32(maxenc[b * 64 + t]);
    __syncthreads();

    // Windows: categorical (exact JAX gumbel) + max + mean pooling. Lanes 0..15.
    if (t < 16) {
        int h2 = t >> 2, w2 = t & 3;
        float win[4], winc[4], sg[4];
#pragma unroll
        for (int j = 0; j < 4; ++j) {
            int hh = 2 * h2 + (j >> 1), ww = 2 * w2 + (j & 1);
            float v = sm[hh * 8 + ww];
            win[j] = v;
            winc[j] = bad_val(v) ? EPSV : v;
            unsigned n = (unsigned)(b * 64 + t * 4 + j);
            unsigned bits = jax_random_bits(n);
            float f = __uint_as_float(0x3F800000u | (bits >> 9)) - 1.0f;
            float u = fmaxf(TINYF, f + TINYF);
            sg[j] = -logf(-logf(u));
        }
        int idx = 0;
        float best = winc[0] + sg[0];
#pragma unroll
        for (int j = 1; j < 4; ++j) {
            float s = winc[j] + sg[j];
            if (s > best) { best = s; idx = j; }
        }
        float mo2 = winc[idx];
        float mo3 = fmaxf(fmaxf(win[0], win[1]), fmaxf(win[2], win[3]));
        float ssum = ((win[0] + win[1]) + win[2]) + win[3];
        float ao4 = ssum * 0.25f;
        sa16[t] = 0.1f * mo2 + 0.6f * mo3 + 0.3f * ao4;
    }
    __syncthreads();

    // 3x3 conv (1->1, SAME, no bias) on 4x4. Lanes 0..15.
    if (t < 16) {
        int i = t >> 2, j = t & 3;
        float acc = 0.0f;
#pragma unroll
        for (int dy = -1; dy <= 1; ++dy) {
            int yy = i + dy;
            if (yy < 0 || yy > 3) continue;
#pragma unroll
            for (int dx = -1; dx <= 1; ++dx) {
                int xx = j + dx;
                if (xx < 0 || xx > 3) continue;
                acc += sa16[yy * 4 + xx] * w11[(dy + 1) * 3 + (dx + 1)];
            }
        }
        sb16[t] = acc;
    }
    __syncthreads();

    // Bilinear resize 4x4 -> 8x8 (align_corners=False). All 64 lanes.
    {
        int y = t >> 3, xx2 = t & 7;
        float sy = (y + 0.5f) * 0.5f - 0.5f;
        float sx = (xx2 + 0.5f) * 0.5f - 0.5f;
        float fy = fminf(fmaxf(sy, 0.0f), 3.0f);
        float fx = fminf(fmaxf(sx, 0.0f), 3.0f);
        int iy0 = (int)floorf(fy); int iy1 = min(iy0 + 1, 3); float ry = fy - (float)iy0;
        int ix0 = (int)floorf(fx); int ix1 = min(ix0 + 1, 3); float rx = fx - (float)ix0;
        float v00 = sb16[iy0 * 4 + ix0], v01 = sb16[iy0 * 4 + ix1];
        float v10 = sb16[iy1 * 4 + ix0], v11 = sb16[iy1 * 4 + ix1];
        float top = v00 * (1.0f - rx) + v01 * rx;
        float bot = v10 * (1.0f - rx) + v11 * rx;
        so2[t] = top * (1.0f - ry) + bot * ry;
    }
    __syncthreads();

    // conv5: [2->4] 3x3 SAME + bias + relu on 8x8 (ch0 = m, ch1 = out2).
    {
        int y = t >> 3, x2 = t & 7;
        float a0 = b5[0], a1 = b5[1], a2 = b5[2], a3 = b5[3];
#pragma unroll
        for (int dy = -1; dy <= 1; ++dy) {
            int yy = y + dy;
            if (yy < 0 || yy > 7) continue;
#pragma unroll
            for (int dx = -1; dx <= 1; ++dx) {
                int xx = x2 + dx;
                if (xx < 0 || xx > 7) continue;
                float i0 = sm[yy * 8 + xx];
                float i1 = so2[yy * 8 + xx];
                int kk = (dy + 1) * 3 + (dx + 1);
                a0 += i0 * w5[0 * 18 + kk] + i1 * w5[0 * 18 + 9 + kk];
                a1 += i0 * w5[1 * 18 + kk] + i1 * w5[1 * 18 + 9 + kk];
                a2 += i0 * w5[2 * 18 + kk] + i1 * w5[2 * 18 + 9 + kk];
                a3 += i0 * w5[3 * 18 + kk] + i1 * w5[3 * 18 + 9 + kk];
            }
        }
        shid[0 * 64 + t] = fmaxf(a0, 0.0f);
        shid[1 * 64 + t] = fmaxf(a1, 0.0f);
        shid[2 * 64 + t] = fmaxf(a2, 0.0f);
        shid[3 * 64 + t] = fmaxf(a3, 0.0f);
    }
    __syncthreads();

    // conv6: [4->1] 3x3 SAME + bias + sigmoid -> gate.
    {
        int y = t >> 3, x2 = t & 7;
        float acc = b6[0];
#pragma unroll
        for (int dy = -1; dy <= 1; ++dy) {
            int yy = y + dy;
            if (yy < 0 || yy > 7) continue;
#pragma unroll
            for (int dx = -1; dx <= 1; ++dx) {
                int xx = x2 + dx;
                if (xx < 0 || xx > 7) continue;
                int kk = (dy + 1) * 3 + (dx + 1);
                int p = yy * 8 + xx;
                acc += shid[0 * 64 + p] * w6[0 + kk]
                     + shid[1 * 64 + p] * w6[9 + kk]
                     + shid[2 * 64 + p] * w6[18 + kk]
                     + shid[3 * 64 + p] * w6[27 + kk];
            }
        }
        gate_out[b * 64 + t] = 1.0f / (1.0f + expf(-acc));
    }
}

// ---- B: out = relu(x * gate). 8 blocks/batch, 32 KB each, nt stores. ------
__global__ __launch_bounds__(256) void sa_apply_kernel(
    const float* __restrict__ x,
    const float* __restrict__ gate,
    float* __restrict__ out)
{
    const int bid = blockIdx.x;       // 4096
    const int t = threadIdx.x;
    const int b = bid >> 3;
    const size_t base = (size_t)bid * 2048;  // float4 units

    const vfloat4* __restrict__ x4 = (const vfloat4*)x;
    vfloat4* __restrict__ o4 = (vfloat4*)out;

    const float4 gv = ((const float4*)(gate + b * 64))[t & 15];

#pragma unroll
    for (int i = 0; i < 8; ++i) {
        size_t idx = base + t + 256 * i;
        vfloat4 v = x4[idx];
        vfloat4 o;
        o.x = fmaxf(v.x * gv.x, 0.0f);
        o.y = fmaxf(v.y * gv.y, 0.0f);
        o.z = fmaxf(v.z * gv.z, 0.0f);
        o.w = fmaxf(v.w * gv.w, 0.0f);
        __builtin_nontemporal_store(o, &o4[idx]);
    }
}

extern "C" void kernel_launch(void* const* d_in, const int* in_sizes, int n_in,
                              void* d_out, int out_size, void* d_ws, size_t ws_size,
                              hipStream_t stream) {
    const float* x   = (const float*)d_in[0];
    const float* w11 = (const float*)d_in[1];
    const float* w5  = (const float*)d_in[2];
    const float* b5  = (const float*)d_in[3];
    const float* w6  = (const float*)d_in[4];
    const float* b6  = (const float*)d_in[5];
    float* out = (float*)d_out;

    int B = in_sizes[0] / (C_DIM * HW);  // 512
    unsigned* maxenc = (unsigned*)d_ws;               // B*64 u32 = 128 KB
    float* gate = (float*)d_ws + (size_t)B * 64;      // B*64 f32 = 128 KB

    // encoded -inf == 0 -> plain memset works as init
    (void)hipMemsetAsync(maxenc, 0, (size_t)B * 64 * sizeof(unsigned), stream);
    sa_max_kernel<<<dim3(B * 4), dim3(256), 0, stream>>>(x, maxenc);
    sa_middle_kernel<<<dim3(B), dim3(64), 0, stream>>>(maxenc, w11, w5, b5, w6, b6, gate);
    sa_apply_kernel<<<dim3(B * 8), dim3(256), 0, stream>>>(x, gate, out);
}

// Round 5
// 260.673 us; speedup vs baseline: 1.0221x; 1.0221x over previous
//
#include <hip/hip_runtime.h>
#include <math.h>

// x [B=512, C=1024, H=8, W=8] f32. out same shape.
#define C_DIM 1024
#define HW 64
#define EPSV 1e-8f
#define TINYF 1.17549435e-38f

typedef float vfloat4 __attribute__((ext_vector_type(4)));

__device__ __forceinline__ void threefry2x32_01(unsigned x0, unsigned x1,
                                                unsigned& o0, unsigned& o1) {
    const unsigned ks0 = 0u, ks1 = 1u, ks2 = 0x1BD11BDBu; // 0x1BD11BDA ^ 0 ^ 1
    x0 += ks0; x1 += ks1;
#define TF_R(r) { x0 += x1; x1 = (x1 << (r)) | (x1 >> (32 - (r))); x1 ^= x0; }
    TF_R(13) TF_R(15) TF_R(26) TF_R(6)
    x0 += ks1; x1 += ks2 + 1u;
    TF_R(17) TF_R(29) TF_R(16) TF_R(24)
    x0 += ks2; x1 += ks0 + 2u;
    TF_R(13) TF_R(15) TF_R(26) TF_R(6)
    x0 += ks0; x1 += ks1 + 3u;
    TF_R(17) TF_R(29) TF_R(16) TF_R(24)
    x0 += ks1; x1 += ks2 + 4u;
    TF_R(13) TF_R(15) TF_R(26) TF_R(6)
    x0 += ks2; x1 += ks0 + 5u;
#undef TF_R
    o0 = x0; o1 = x1;
}

// jax_threefry_partitionable=True: counter (hi=0, lo=n), out = o0 ^ o1.
__device__ __forceinline__ unsigned jax_random_bits(unsigned n) {
    unsigned o0, o1;
    threefry2x32_01(0u, n, o0, o1);
    return o0 ^ o1;
}

__device__ __forceinline__ bool bad_val(float v) {
    return ((__float_as_uint(v) & 0x7F800000u) == 0x7F800000u) || (v < 0.0f);
}

// ---- A: channel-max partials. 4 blocks/batch, 64 KB stream each. ----------
// Block bid writes its own partial slot: full coverage -> no init, no atomics.
__global__ __launch_bounds__(256, 8) void sa_max_part(
    const float* __restrict__ x, float4* __restrict__ part)
{
    const int bid = blockIdx.x;       // 2048
    const int t = threadIdx.x;
    const float4* __restrict__ xb = (const float4*)x + (size_t)bid * 4096;

    float4 pm = make_float4(-INFINITY, -INFINITY, -INFINITY, -INFINITY);
#pragma unroll
    for (int i = 0; i < 16; ++i) {
        float4 v = xb[t + 256 * i];
        pm.x = fmaxf(pm.x, v.x); pm.y = fmaxf(pm.y, v.y);
        pm.z = fmaxf(pm.z, v.z); pm.w = fmaxf(pm.w, v.w);
    }
    // reduce lanes with same (t&15) within the wave
#pragma unroll
    for (int off = 16; off <= 32; off <<= 1) {
        pm.x = fmaxf(pm.x, __shfl_xor(pm.x, off, 64));
        pm.y = fmaxf(pm.y, __shfl_xor(pm.y, off, 64));
        pm.z = fmaxf(pm.z, __shfl_xor(pm.z, off, 64));
        pm.w = fmaxf(pm.w, __shfl_xor(pm.w, off, 64));
    }
    __shared__ float4 red[4][16];
    const int wv = t >> 6, lane = t & 63;
    if (lane < 16) red[wv][lane] = pm;
    __syncthreads();
    if (t < 16) {
        float4 a = red[0][t];
#pragma unroll
        for (int w = 1; w < 4; ++w) {
            float4 o = red[w][t];
            a.x = fmaxf(a.x, o.x); a.y = fmaxf(a.y, o.y);
            a.z = fmaxf(a.z, o.z); a.w = fmaxf(a.w, o.w);
        }
        part[bid * 16 + t] = a;   // part[bid][64] floats
    }
}

// ---- B: fused gate (redundant per block) + apply. 8 blocks/batch. ---------
__global__ __launch_bounds__(256, 4) void sa_gate_apply(
    const float* __restrict__ x,
    const float* __restrict__ part,
    const float* __restrict__ w11,
    const float* __restrict__ w5,
    const float* __restrict__ b5,
    const float* __restrict__ w6,
    const float* __restrict__ b6,
    float* __restrict__ out)
{
    const int bid = blockIdx.x;       // 4096
    const int t = threadIdx.x;
    const int b = bid >> 3;
    const size_t base = (size_t)bid * 2048;  // float4 units

    const vfloat4* __restrict__ x4 = (const vfloat4*)x;
    vfloat4* __restrict__ o4 = (vfloat4*)out;

    // Issue all x loads up front; middle overlaps their latency.
    vfloat4 v[8];
#pragma unroll
    for (int i = 0; i < 8; ++i) v[i] = x4[base + t + 256 * i];

    __shared__ float sm[64];
    __shared__ float sa16[16];
    __shared__ float sb16[16];
    __shared__ float so2[64];
    __shared__ float shid[4 * 64];
    __shared__ __align__(16) float sgate[64];

    if (t < 64) {
        // Reduce the 4 quarter-partials for this batch.
        const float* pb = part + b * 256;
        sm[t] = fmaxf(fmaxf(pb[t], pb[64 + t]),
                      fmaxf(pb[128 + t], pb[192 + t]));
        __builtin_amdgcn_wave_barrier();

        // Windows: categorical (exact JAX gumbel) + max + mean. Lanes 0..15.
        if (t < 16) {
            int h2 = t >> 2, w2 = t & 3;
            float win[4], winc[4], sg[4];
#pragma unroll
            for (int j = 0; j < 4; ++j) {
                int hh = 2 * h2 + (j >> 1), ww = 2 * w2 + (j & 1);
                float vv = sm[hh * 8 + ww];
                win[j] = vv;
                winc[j] = bad_val(vv) ? EPSV : vv;
                unsigned n = (unsigned)(b * 64 + t * 4 + j);
                unsigned bits = jax_random_bits(n);
                float f = __uint_as_float(0x3F800000u | (bits >> 9)) - 1.0f;
                float u = fmaxf(TINYF, f + TINYF);
                sg[j] = -logf(-logf(u));
            }
            int idx = 0;
            float best = winc[0] + sg[0];
#pragma unroll
            for (int j = 1; j < 4; ++j) {
                float s = winc[j] + sg[j];
                if (s > best) { best = s; idx = j; }
            }
            float mo2 = winc[idx];
            float mo3 = fmaxf(fmaxf(win[0], win[1]), fmaxf(win[2], win[3]));
            float ssum = ((win[0] + win[1]) + win[2]) + win[3];
            float ao4 = ssum * 0.25f;
            sa16[t] = 0.1f * mo2 + 0.6f * mo3 + 0.3f * ao4;
        }
        __builtin_amdgcn_wave_barrier();

        // 3x3 conv (1->1, SAME, no bias) on 4x4. Lanes 0..15.
        if (t < 16) {
            int i = t >> 2, j = t & 3;
            float acc = 0.0f;
#pragma unroll
            for (int dy = -1; dy <= 1; ++dy) {
                int yy = i + dy;
                if (yy < 0 || yy > 3) continue;
#pragma unroll
                for (int dx = -1; dx <= 1; ++dx) {
                    int xx = j + dx;
                    if (xx < 0 || xx > 3) continue;
                    acc += sa16[yy * 4 + xx] * w11[(dy + 1) * 3 + (dx + 1)];
                }
            }
            sb16[t] = acc;
        }
        __builtin_amdgcn_wave_barrier();

        // Bilinear resize 4x4 -> 8x8 (align_corners=False). All 64 lanes.
        {
            int y = t >> 3, xx2 = t & 7;
            float sy = (y + 0.5f) * 0.5f - 0.5f;
            float sx = (xx2 + 0.5f) * 0.5f - 0.5f;
            float fy = fminf(fmaxf(sy, 0.0f), 3.0f);
            float fx = fminf(fmaxf(sx, 0.0f), 3.0f);
            int iy0 = (int)floorf(fy); int iy1 = min(iy0 + 1, 3); float ry = fy - (float)iy0;
            int ix0 = (int)floorf(fx); int ix1 = min(ix0 + 1, 3); float rx = fx - (float)ix0;
            float v00 = sb16[iy0 * 4 + ix0], v01 = sb16[iy0 * 4 + ix1];
            float v10 = sb16[iy1 * 4 + ix0], v11 = sb16[iy1 * 4 + ix1];
            float top = v00 * (1.0f - rx) + v01 * rx;
            float bot = v10 * (1.0f - rx) + v11 * rx;
            so2[t] = top * (1.0f - ry) + bot * ry;
        }
        __builtin_amdgcn_wave_barrier();

        // conv5: [2->4] 3x3 SAME + bias + relu on 8x8 (ch0 = m, ch1 = out2).
        {
            int y = t >> 3, x2 = t & 7;
            float a0 = b5[0], a1 = b5[1], a2 = b5[2], a3 = b5[3];
#pragma unroll
            for (int dy = -1; dy <= 1; ++dy) {
                int yy = y + dy;
                if (yy < 0 || yy > 7) continue;
#pragma unroll
                for (int dx = -1; dx <= 1; ++dx) {
                    int xx = x2 + dx;
                    if (xx < 0 || xx > 7) continue;
                    float i0 = sm[yy * 8 + xx];
                    float i1 = so2[yy * 8 + xx];
                    int kk = (dy + 1) * 3 + (dx + 1);
                    a0 += i0 * w5[0 * 18 + kk] + i1 * w5[0 * 18 + 9 + kk];
                    a1 += i0 * w5[1 * 18 + kk] + i1 * w5[1 * 18 + 9 + kk];
                    a2 += i0 * w5[2 * 18 + kk] + i1 * w5[2 * 18 + 9 + kk];
                    a3 += i0 * w5[3 * 18 + kk] + i1 * w5[3 * 18 + 9 + kk];
                }
            }
            shid[0 * 64 + t] = fmaxf(a0, 0.0f);
            shid[1 * 64 + t] = fmaxf(a1, 0.0f);
            shid[2 * 64 + t] = fmaxf(a2, 0.0f);
            shid[3 * 64 + t] = fmaxf(a3, 0.0f);
        }
        __builtin_amdgcn_wave_barrier();

        // conv6: [4->1] 3x3 SAME + bias + sigmoid -> gate.
        {
            int y = t >> 3, x2 = t & 7;
            float acc = b6[0];
#pragma unroll
            for (int dy = -1; dy <= 1; ++dy) {
                int yy = y + dy;
                if (yy < 0 || yy > 7) continue;
#pragma unroll
                for (int dx = -1; dx <= 1; ++dx) {
                    int xx = x2 + dx;
                    if (xx < 0 || xx > 7) continue;
                    int kk = (dy + 1) * 3 + (dx + 1);
                    int p = yy * 8 + xx;
                    acc += shid[0 * 64 + p] * w6[0 + kk]
                         + shid[1 * 64 + p] * w6[9 + kk]
                         + shid[2 * 64 + p] * w6[18 + kk]
                         + shid[3 * 64 + p] * w6[27 + kk];
                }
            }
            sgate[t] = 1.0f / (1.0f + expf(-acc));
        }
    }
    __syncthreads();

    const float4 gv = ((const float4*)sgate)[t & 15];
#pragma unroll
    for (int i = 0; i < 8; ++i) {
        vfloat4 o;
        o.x = fmaxf(v[i].x * gv.x, 0.0f);
        o.y = fmaxf(v[i].y * gv.y, 0.0f);
        o.z = fmaxf(v[i].z * gv.z, 0.0f);
        o.w = fmaxf(v[i].w * gv.w, 0.0f);
        o4[base + t + 256 * i] = o;
    }
}

extern "C" void kernel_launch(void* const* d_in, const int* in_sizes, int n_in,
                              void* d_out, int out_size, void* d_ws, size_t ws_size,
                              hipStream_t stream) {
    const float* x   = (const float*)d_in[0];
    const float* w11 = (const float*)d_in[1];
    const float* w5  = (const float*)d_in[2];
    const float* b5  = (const float*)d_in[3];
    const float* w6  = (const float*)d_in[4];
    const float* b6  = (const float*)d_in[5];
    float* out = (float*)d_out;

    int B = in_sizes[0] / (C_DIM * HW);  // 512
    float4* part = (float4*)d_ws;        // B*4 blocks × 64 floats = 512 KB

    sa_max_part<<<dim3(B * 4), dim3(256), 0, stream>>>(x, part);
    sa_gate_apply<<<dim3(B * 8), dim3(256), 0, stream>>>(
        x, (const float*)part, w11, w5, b5, w6, b6, out);
}